// Round 4
// baseline (681.004 us; speedup 1.0000x reference)
//
#include <hip/hip_runtime.h>

// ---- filter / neuron constants (double, matching the Python reference) ----
#define EMD 0.8824969025845955      // exp(-1/8)
#define ESD 0.6065306597126334      // exp(-1/2)
#define A1C ((float)(EMD + ESD))                    // y[t-1] coeff
#define A2C ((float)(-(EMD * ESD)))                 // y[t-2] coeff
#define BC  ((float)((8.0 / 6.0) * (EMD - ESD)))    // x[t] coeff (ETA=8/6)
#define EMF ((float)EMD)                            // reset decay

// B=64, T=300. Layers: 300 -> 500 -> 200 -> 500 -> 300.
// IIR commutes with the GEMM (uniform per-feature coefficients, zero init),
// so GEMMs run on raw binary spikes and the IIR folds into the LIF pass.
// Accumulation strictly sequential in k (zero-padded tails: acc += w*0 is
// bitwise-neutral) -> absmax 0.0 in rounds 1-3; preserve in every variant.

// ---------------------------------------------------------------------------
// GEMM: C[b,o,t] = sum_i W[o,i] * X[b,i,t]
// X: [B,K,T] (T contiguous), W: [O,K], C: [B,O,T]
// SINGLE-WAVE blocks (64 threads), 64x64 tile, 8o x 8t microtile, KC=8.
// Double-buffered LDS + register prefetch, NO barriers: DS ops are in-order
// per wave, and with one wave/block there is no cross-wave hazard. Global
// loads for tile c+1 issue before the tile-c FMA block; their vmcnt wait sits
// in the ds_write after the FMAs -> staging latency overlaps compute.
// ---------------------------------------------------------------------------
#define KC 8
#define BM 64
#define BN 64

__global__ __launch_bounds__(64) void gemm_snn(
    const float* __restrict__ X, const float* __restrict__ W,
    float* __restrict__ C, int K, int O, int T)
{
    __shared__ float As[2][KC][BM];   // [buf][k][o], row 256 B
    __shared__ float Bs[2][KC][BN];   // [buf][k][t]

    const int lane = threadIdx.x;      // 0..63
    const int tx   = lane & 7;         // 8 t's per lane
    const int ty   = lane >> 3;        // 8 o's per lane
    const int o0   = blockIdx.x * BM;
    const int t0   = blockIdx.y * BN;
    const int b    = blockIdx.z;
    const float* Xb = X + (size_t)b * K * T;

    // staging decomposition (per round: A tile 64o x 8k, B tile 8k x 64t)
    const int akq = lane & 1;          // which float4 along k (0..1)
    const int aol = lane >> 1;         // o (0..31), +32 on pass 2
    const int btq = lane & 15;         // float4 along t (0..15)
    const int bkl = lane >> 4;         // k row (0..3), +4 on pass 2

    const int nk = (K + KC - 1) / KC;

    float4 apf0, apf1, bpf0, bpf1;     // prefetch registers

#define LOAD_TILE(c)                                                           \
    {                                                                          \
        const int k0 = (c) * KC;                                               \
        const int ka = k0 + akq * 4;                                           \
        const int oa = o0 + aol;                                               \
        apf0 = make_float4(0.f, 0.f, 0.f, 0.f);                                \
        apf1 = make_float4(0.f, 0.f, 0.f, 0.f);                                \
        if (ka + 3 < K) {                                                      \
            if (oa < O)                                                        \
                apf0 = *reinterpret_cast<const float4*>(&W[(size_t)oa * K + ka]); \
            if (oa + 32 < O)                                                   \
                apf1 = *reinterpret_cast<const float4*>(&W[(size_t)(oa + 32) * K + ka]); \
        }                                                                      \
        const int tb = t0 + btq * 4;                                           \
        bpf0 = make_float4(0.f, 0.f, 0.f, 0.f);                                \
        bpf1 = make_float4(0.f, 0.f, 0.f, 0.f);                                \
        if (tb + 3 < T) {                                                      \
            if (k0 + bkl < K)                                                  \
                bpf0 = *reinterpret_cast<const float4*>(&Xb[(size_t)(k0 + bkl) * T + tb]); \
            if (k0 + bkl + 4 < K)                                              \
                bpf1 = *reinterpret_cast<const float4*>(&Xb[(size_t)(k0 + bkl + 4) * T + tb]); \
        }                                                                      \
    }

#define STORE_TILE(buf)                                                        \
    {                                                                          \
        As[buf][akq * 4 + 0][aol]      = apf0.x;                               \
        As[buf][akq * 4 + 1][aol]      = apf0.y;                               \
        As[buf][akq * 4 + 2][aol]      = apf0.z;                               \
        As[buf][akq * 4 + 3][aol]      = apf0.w;                               \
        As[buf][akq * 4 + 0][aol + 32] = apf1.x;                               \
        As[buf][akq * 4 + 1][aol + 32] = apf1.y;                               \
        As[buf][akq * 4 + 2][aol + 32] = apf1.z;                               \
        As[buf][akq * 4 + 3][aol + 32] = apf1.w;                               \
        *reinterpret_cast<float4*>(&Bs[buf][bkl][btq * 4])     = bpf0;         \
        *reinterpret_cast<float4*>(&Bs[buf][bkl + 4][btq * 4]) = bpf1;         \
    }

    float acc[8][8] = {};

    LOAD_TILE(0)
    STORE_TILE(0)

    for (int c = 0; c < nk; c++) {
        const int cur = c & 1;
        if (c + 1 < nk) LOAD_TILE(c + 1)        // async; consumed after FMAs
#pragma unroll
        for (int k = 0; k < KC; k++) {
            const float4 a0 = *reinterpret_cast<const float4*>(&As[cur][k][ty * 8]);
            const float4 a1 = *reinterpret_cast<const float4*>(&As[cur][k][ty * 8 + 4]);
            const float4 x0 = *reinterpret_cast<const float4*>(&Bs[cur][k][tx * 8]);
            const float4 x1 = *reinterpret_cast<const float4*>(&Bs[cur][k][tx * 8 + 4]);
            const float av[8] = {a0.x, a0.y, a0.z, a0.w, a1.x, a1.y, a1.z, a1.w};
            const float xv[8] = {x0.x, x0.y, x0.z, x0.w, x1.x, x1.y, x1.z, x1.w};
#pragma unroll
            for (int i = 0; i < 8; i++) {
#pragma unroll
                for (int j = 0; j < 8; j++) acc[i][j] += av[i] * xv[j];
            }
        }
        if (c + 1 < nk) STORE_TILE((c + 1) & 1)  // other buffer: no hazard
        __builtin_amdgcn_wave_barrier();         // compiler-only fence, free
    }

    float* Cb = C + (size_t)b * O * T;
#pragma unroll
    for (int i = 0; i < 8; i++) {
        const int o = o0 + ty * 8 + i;
        if (o < O) {
            float* Crow = Cb + (size_t)o * T + t0 + tx * 8;
            const int t = t0 + tx * 8;
            if (t + 3 < T)
                *reinterpret_cast<float4*>(Crow) =
                    make_float4(acc[i][0], acc[i][1], acc[i][2], acc[i][3]);
            if (t + 7 < T)
                *reinterpret_cast<float4*>(Crow + 4) =
                    make_float4(acc[i][4], acc[i][5], acc[i][6], acc[i][7]);
        }
    }
}

// ---------------------------------------------------------------------------
// Fused IIR + bias + LIF (in-place). One thread per (b,o) chain, T=300 fixed.
// Ring-4 float4 prefetch with UNROLLED (constant) ring indices so the buffer
// lives in VGPRs (a dynamic index would force scratch). 75 = 18*4 + 3.
// ---------------------------------------------------------------------------
#define LIF_STEP(comp)                                                         \
    {                                                                          \
        float y = A1 * y1 + A2 * y2 + Bc * x.comp; y2 = y1; y1 = y;            \
        const float v = y + bi + r;                                            \
        const float s = (v >= 1.0f) ? 1.0f : 0.0f;                             \
        r = r * EMF - s; x.comp = s;                                           \
    }

__global__ __launch_bounds__(64) void lif_snn(
    float* __restrict__ C, const float* __restrict__ bias,
    const float* __restrict__ a1p, const float* __restrict__ a2p,
    const float* __restrict__ bp, int BO, int O)
{
    const int idx = blockIdx.x * 64 + threadIdx.x;
    if (idx >= BO) return;
    const float A1 = a1p[0], A2 = a2p[0], Bc = bp[0];
    const float bi = bias[idx % O];
    float4* row = reinterpret_cast<float4*>(C) + (size_t)idx * 75;

    float4 buf[4];
#pragma unroll
    for (int p = 0; p < 4; p++) buf[p] = row[p];

    float y1 = 0.0f, y2 = 0.0f, r = 0.0f;
    for (int blk = 0; blk < 18; blk++) {
#pragma unroll
        for (int u = 0; u < 4; u++) {
            const int q = blk * 4 + u;
            float4 x = buf[u];
            const int qn = q + 4;
            if (qn < 75) buf[u] = row[qn];
            LIF_STEP(x) LIF_STEP(y) LIF_STEP(z) LIF_STEP(w)
            row[q] = x;
        }
    }
#pragma unroll
    for (int u = 0; u < 3; u++) {
        float4 x = buf[u];
        LIF_STEP(x) LIF_STEP(y) LIF_STEP(z) LIF_STEP(w)
        row[72 + u] = x;
    }
}

// ---------------------------------------------------------------------------
// Layer-4 LIF fused with the fixed output dual-exp IIR filter.
// C: currents in / spikes out (first half of d_out); F: filt (second half).
// ---------------------------------------------------------------------------
#define OUT_STEP(comp)                                                         \
    { float z = A1C * z1 + A2C * z2 + BC * x.comp; z2 = z1; z1 = z; f.comp = z; }

__global__ __launch_bounds__(64) void lif4_snn(
    float* __restrict__ C, float* __restrict__ F,
    const float* __restrict__ bias,
    const float* __restrict__ a1p, const float* __restrict__ a2p,
    const float* __restrict__ bp, int BO, int O)
{
    const int idx = blockIdx.x * 64 + threadIdx.x;
    if (idx >= BO) return;
    const float A1 = a1p[0], A2 = a2p[0], Bc = bp[0];
    const float bi = bias[idx % O];
    float4* row  = reinterpret_cast<float4*>(C) + (size_t)idx * 75;
    float4* frow = reinterpret_cast<float4*>(F) + (size_t)idx * 75;

    float4 buf[4];
#pragma unroll
    for (int p = 0; p < 4; p++) buf[p] = row[p];

    float y1 = 0.0f, y2 = 0.0f, r = 0.0f;   // layer IIR + reset state
    float z1 = 0.0f, z2 = 0.0f;             // output-filter IIR state
    for (int blk = 0; blk < 18; blk++) {
#pragma unroll
        for (int u = 0; u < 4; u++) {
            const int q = blk * 4 + u;
            float4 x = buf[u];
            const int qn = q + 4;
            if (qn < 75) buf[u] = row[qn];
            float4 f;
            LIF_STEP(x) OUT_STEP(x)
            LIF_STEP(y) OUT_STEP(y)
            LIF_STEP(z) OUT_STEP(z)
            LIF_STEP(w) OUT_STEP(w)
            row[q]  = x;
            frow[q] = f;
        }
    }
#pragma unroll
    for (int u = 0; u < 3; u++) {
        float4 x = buf[u];
        float4 f;
        LIF_STEP(x) OUT_STEP(x)
        LIF_STEP(y) OUT_STEP(y)
        LIF_STEP(z) OUT_STEP(z)
        LIF_STEP(w) OUT_STEP(w)
        row[72 + u]  = x;
        frow[72 + u] = f;
    }
}

// ---------------------------------------------------------------------------
extern "C" void kernel_launch(void* const* d_in, const int* in_sizes, int n_in,
                              void* d_out, int out_size, void* d_ws, size_t ws_size,
                              hipStream_t stream)
{
    const float* inputs = (const float*)d_in[0];           // [64,300,300] binary
    const float* a1_1 = (const float*)d_in[1];
    const float* a2_1 = (const float*)d_in[2];
    const float* b_1  = (const float*)d_in[3];
    const float* W1   = (const float*)d_in[4];             // [500,300]
    const float* bias1= (const float*)d_in[5];
    const float* a1_2 = (const float*)d_in[6];
    const float* a2_2 = (const float*)d_in[7];
    const float* b_2  = (const float*)d_in[8];
    const float* W2   = (const float*)d_in[9];             // [200,500]
    const float* bias2= (const float*)d_in[10];
    const float* a1_3 = (const float*)d_in[11];
    const float* a2_3 = (const float*)d_in[12];
    const float* b_3  = (const float*)d_in[13];
    const float* W3   = (const float*)d_in[14];            // [500,200]
    const float* bias3= (const float*)d_in[15];
    const float* a1_4 = (const float*)d_in[16];
    const float* a2_4 = (const float*)d_in[17];
    const float* b_4  = (const float*)d_in[18];
    const float* W4   = (const float*)d_in[19];            // [300,500]
    const float* bias4= (const float*)d_in[20];

    const int B = 64, T = 300;

    float* ws = (float*)d_ws;
    float* c1 = ws;                         // [64,500,300] (currents -> spikes, layers 1/3)
    float* c2 = ws + 9600000;               // [64,200,300]
    float* out = (float*)d_out;
    float* s4   = out;                      // [64,300,300]
    float* filt = out + 5760000;            // [64,300,300]

    // Grid: x = o-tiles (fastest -> concurrent blocks share the X tile in L2),
    // y = t-tiles, z = b. Single-wave (64-thread) blocks.
    // Layer 1: 300 -> 500
    gemm_snn<<<dim3(8, 5, B), 64, 0, stream>>>(inputs, W1, c1, 300, 500, T);
    lif_snn<<<500, 64, 0, stream>>>(c1, bias1, a1_1, a2_1, b_1, B * 500, 500);
    // Layer 2: 500 -> 200
    gemm_snn<<<dim3(4, 5, B), 64, 0, stream>>>(c1, W2, c2, 500, 200, T);
    lif_snn<<<200, 64, 0, stream>>>(c2, bias2, a1_2, a2_2, b_2, B * 200, 200);
    // Layer 3: 200 -> 500 (reuse c1; s1 dead)
    gemm_snn<<<dim3(8, 5, B), 64, 0, stream>>>(c2, W3, c1, 200, 500, T);
    lif_snn<<<500, 64, 0, stream>>>(c1, bias3, a1_3, a2_3, b_3, B * 500, 500);
    // Layer 4: 500 -> 300, currents into d_out; fused LIF + output filter
    gemm_snn<<<dim3(5, 5, B), 64, 0, stream>>>(c1, W4, s4, 500, 300, T);
    lif4_snn<<<300, 64, 0, stream>>>(s4, filt, bias4, a1_4, a2_4, b_4, B * 300, 300);
}

// Round 5
// 624.564 us; speedup vs baseline: 1.0904x; 1.0904x over previous
//
#include <hip/hip_runtime.h>

// ---- filter / neuron constants (double, matching the Python reference) ----
#define EMD 0.8824969025845955      // exp(-1/8)
#define ESD 0.6065306597126334      // exp(-1/2)
#define A1C ((float)(EMD + ESD))                    // y[t-1] coeff
#define A2C ((float)(-(EMD * ESD)))                 // y[t-2] coeff
#define BC  ((float)((8.0 / 6.0) * (EMD - ESD)))    // x[t] coeff (ETA=8/6)
#define EMF ((float)EMD)                            // reset decay

// B=64, T=300. Layers: 300 -> 500 -> 200 -> 500 -> 300.
//
// Exactness contract (absmax 0.0 in rounds 1-4): reference currents are a
// SEQUENTIAL ascending-i fp32 fold of W[o,i]*s[i]. Skipping s==0 terms is
// bitwise-neutral (x + (+/-0) = x; +0 + (+/-0) = +0), so a sparse ascending-i
// gather-sum is EXACT. MFMA / reordered sums are NOT (spike flips near v==1).
//
// Layout: all intermediates time-major [B,T,F]; the sparse GEMM writes
// coalesced current rows, the ballot reads coalesced spike rows. Final
// outputs transposed back to [B,O,T].

// ---------------------------------------------------------------------------
// Generic batched transpose: src [Bt][R][C] -> dst [Bt][C][R]
// ---------------------------------------------------------------------------
__global__ __launch_bounds__(256) void transpose_rc(
    const float* __restrict__ src, float* __restrict__ dst, int R, int C)
{
    __shared__ float tile[32][33];
    const int c0 = blockIdx.x * 32;
    const int r0 = blockIdx.y * 32;
    const int b  = blockIdx.z;
    const float* S = src + (size_t)b * R * C;
    float* D = dst + (size_t)b * R * C;
    const int tx = threadIdx.x;      // 0..31
    const int ty = threadIdx.y;      // 0..7
#pragma unroll
    for (int s = 0; s < 4; s++) {
        const int r = r0 + ty + 8 * s;
        const int c = c0 + tx;
        if (r < R && c < C) tile[ty + 8 * s][tx] = S[(size_t)r * C + c];
    }
    __syncthreads();
#pragma unroll
    for (int s = 0; s < 4; s++) {
        const int c = c0 + ty + 8 * s;
        const int r = r0 + tx;
        if (c < C && r < R) D[(size_t)c * R + r] = tile[tx][ty + 8 * s];
    }
}

// ---------------------------------------------------------------------------
// Sparse spike GEMM: C[b,t,o] = sum_i Wt[i,o] * S[b,t,i], skipping S==0.
// S: [B,T,K] binary, Wt: [K,O], C: [B,T,O].
// Block: 256 thr (4 waves), o-chunk 128 (2 o's/lane), t-chunk 32 (8 t/wave),
// K staged in 64-row LDS chunks (32 KB). Per (wave,t,kchunk): wave reads 64
// spikes coalesced, __ballot -> uniform 64-bit mask, iterates set bits in
// ascending order adding Wls[j][2*lane..+1]. Ascending (kc, j) == ascending i.
// ---------------------------------------------------------------------------
#define KG  64
#define OCN 128
#define TCN 32

__global__ __launch_bounds__(256) void spmm_snn(
    const float* __restrict__ S, const float* __restrict__ Wt,
    float* __restrict__ C, int K, int O, int T)
{
    __shared__ float Wls[KG][OCN];   // 32 KB
    const int tid  = threadIdx.x;
    const int lane = tid & 63;
    const int wv   = tid >> 6;       // 0..3
    const int oc   = blockIdx.x * OCN;
    const int t0   = blockIdx.y * TCN;
    const int b    = blockIdx.z;

    const float* Sb = S + (size_t)b * T * K;
    float* Cb = C + (size_t)b * T * O;

    float2 acc[8];
#pragma unroll
    for (int u = 0; u < 8; u++) acc[u] = make_float2(0.f, 0.f);

    const int nkc = (K + KG - 1) / KG;
    for (int kc = 0; kc < nkc; kc++) {
        const int kbase = kc * KG;
        // stage Wt[kbase..+63][oc..+127]; O%4==0 so float4 never straddles O
#pragma unroll
        for (int r = 0; r < 8; r++) {
            const int idx  = tid + r * 256;
            const int row  = idx >> 5;        // 0..63
            const int col4 = (idx & 31) * 4;  // 0..124
            const int k = kbase + row;
            const int o = oc + col4;
            float4 w = make_float4(0.f, 0.f, 0.f, 0.f);
            if (k < K && o + 3 < O)
                w = *reinterpret_cast<const float4*>(&Wt[(size_t)k * O + o]);
            *reinterpret_cast<float4*>(&Wls[row][col4]) = w;
        }
        __syncthreads();
#pragma unroll
        for (int u = 0; u < 8; u++) {
            const int t = t0 + u * 4 + wv;    // wave-uniform -> ballot-safe
            if (t < T) {
                const int k = kbase + lane;
                const float s = (k < K) ? Sb[(size_t)t * K + k] : 0.0f;
                unsigned long long mask = __ballot(s != 0.0f);
                while (mask) {
                    const int j = __builtin_ctzll(mask);
                    mask &= mask - 1;
                    const float2 w =
                        *reinterpret_cast<const float2*>(&Wls[j][lane * 2]);
                    acc[u].x += w.x;
                    acc[u].y += w.y;
                }
            }
        }
        __syncthreads();
    }
#pragma unroll
    for (int u = 0; u < 8; u++) {
        const int t = t0 + u * 4 + wv;
        const int o = oc + lane * 2;
        if (t < T && o + 1 < O)               // O even -> pair all-or-nothing
            *reinterpret_cast<float2*>(&Cb[(size_t)t * O + o]) = acc[u];
    }
}

// ---------------------------------------------------------------------------
// LIF in time-major layout, in-place: C[b,t,o] currents -> spikes.
// One thread per (b,o); strided (stride O) column walk with 8-deep unrolled
// prefetch ring (constant indices -> stays in VGPRs). T fixed at 300.
// ---------------------------------------------------------------------------
#define LIF_STEP_S(xval, sval)                                                 \
    {                                                                          \
        const float y = A1 * y1 + A2 * y2 + Bc * (xval); y2 = y1; y1 = y;      \
        const float v = y + bi + r;                                            \
        sval = (v >= 1.0f) ? 1.0f : 0.0f;                                      \
        r = r * EMF - sval;                                                    \
    }

__global__ __launch_bounds__(64) void lif_t(
    float* __restrict__ C, const float* __restrict__ bias,
    const float* __restrict__ a1p, const float* __restrict__ a2p,
    const float* __restrict__ bp, int O)
{
    const int o = blockIdx.x * 64 + threadIdx.x;
    const int b = blockIdx.y;
    if (o >= O) return;
    const float A1 = a1p[0], A2 = a2p[0], Bc = bp[0];
    const float bi = bias[o];
    float* col = C + (size_t)b * 300 * O + o;

    float pf[8];
#pragma unroll
    for (int u = 0; u < 8; u++) pf[u] = col[(size_t)u * O];

    float y1 = 0.f, y2 = 0.f, r = 0.f;
    for (int blk = 0; blk < 37; blk++) {       // t = 0..295
#pragma unroll
        for (int u = 0; u < 8; u++) {
            const int t = blk * 8 + u;
            const float x = pf[u];
            if (t + 8 < 300) pf[u] = col[(size_t)(t + 8) * O];
            float s;
            LIF_STEP_S(x, s)
            col[(size_t)t * O] = s;
        }
    }
#pragma unroll
    for (int u = 0; u < 4; u++) {              // t = 296..299
        const float x = pf[u];
        float s;
        LIF_STEP_S(x, s)
        col[(size_t)(296 + u) * O] = s;
    }
}

// ---------------------------------------------------------------------------
// Layer-4 LIF + fixed output dual-exp IIR. C: currents->spikes (in place),
// F: filtered output. Both [B,T,O], O=300.
// ---------------------------------------------------------------------------
__global__ __launch_bounds__(64) void lif4_t(
    float* __restrict__ C, float* __restrict__ F,
    const float* __restrict__ bias,
    const float* __restrict__ a1p, const float* __restrict__ a2p,
    const float* __restrict__ bp, int O)
{
    const int o = blockIdx.x * 64 + threadIdx.x;
    const int b = blockIdx.y;
    if (o >= O) return;
    const float A1 = a1p[0], A2 = a2p[0], Bc = bp[0];
    const float bi = bias[o];
    float* col  = C + (size_t)b * 300 * O + o;
    float* fcol = F + (size_t)b * 300 * O + o;

    float pf[8];
#pragma unroll
    for (int u = 0; u < 8; u++) pf[u] = col[(size_t)u * O];

    float y1 = 0.f, y2 = 0.f, r = 0.f;
    float z1 = 0.f, z2 = 0.f;
    for (int blk = 0; blk < 37; blk++) {
#pragma unroll
        for (int u = 0; u < 8; u++) {
            const int t = blk * 8 + u;
            const float x = pf[u];
            if (t + 8 < 300) pf[u] = col[(size_t)(t + 8) * O];
            float s;
            LIF_STEP_S(x, s)
            const float z = A1C * z1 + A2C * z2 + BC * s; z2 = z1; z1 = z;
            col[(size_t)t * O]  = s;
            fcol[(size_t)t * O] = z;
        }
    }
#pragma unroll
    for (int u = 0; u < 4; u++) {
        const int t = 296 + u;
        const float x = pf[u];
        float s;
        LIF_STEP_S(x, s)
        const float z = A1C * z1 + A2C * z2 + BC * s; z2 = z1; z1 = z;
        col[(size_t)t * O]  = s;
        fcol[(size_t)t * O] = z;
    }
}

// ---------------------------------------------------------------------------
extern "C" void kernel_launch(void* const* d_in, const int* in_sizes, int n_in,
                              void* d_out, int out_size, void* d_ws, size_t ws_size,
                              hipStream_t stream)
{
    const float* inputs = (const float*)d_in[0];           // [64,300,300] binary
    const float* a1_1 = (const float*)d_in[1];
    const float* a2_1 = (const float*)d_in[2];
    const float* b_1  = (const float*)d_in[3];
    const float* W1   = (const float*)d_in[4];             // [500,300]
    const float* bias1= (const float*)d_in[5];
    const float* a1_2 = (const float*)d_in[6];
    const float* a2_2 = (const float*)d_in[7];
    const float* b_2  = (const float*)d_in[8];
    const float* W2   = (const float*)d_in[9];             // [200,500]
    const float* bias2= (const float*)d_in[10];
    const float* a1_3 = (const float*)d_in[11];
    const float* a2_3 = (const float*)d_in[12];
    const float* b_3  = (const float*)d_in[13];
    const float* W3   = (const float*)d_in[14];            // [500,200]
    const float* bias3= (const float*)d_in[15];
    const float* a1_4 = (const float*)d_in[16];
    const float* a2_4 = (const float*)d_in[17];
    const float* b_4  = (const float*)d_in[18];
    const float* W4   = (const float*)d_in[19];            // [300,500]
    const float* bias4= (const float*)d_in[20];

    const int B = 64, T = 300;

    // Workspace (proven size 53.76 MB): c1 = 9.6M floats, c2 = 3.84M floats.
    float* ws = (float*)d_ws;
    float* c1 = ws;                 // [B,T,500]; later filt_tmp [B,T,300]
    float* c2 = ws + 9600000;       // [B,T,200]

    // d_out regions double as scratch until the final transposes:
    // region1 [0..5.76M): Wt1..4 (500K floats), later final s4 [B,O,T]
    // region2 [5.76M..11.52M): inputT/c4/s4_tmp [B,T,300], later final filt
    float* out = (float*)d_out;
    float* reg1 = out;
    float* reg2 = out + 5760000;
    float* Wt1 = reg1;              // [300,500] = 150000
    float* Wt2 = reg1 + 150000;     // [500,200] = 100000
    float* Wt3 = reg1 + 250000;     // [200,500] = 100000
    float* Wt4 = reg1 + 350000;     // [500,300] = 150000

    const dim3 tb(32, 8);

    // Weight transposes W[O,K] -> Wt[K,O]
    transpose_rc<<<dim3(10, 16, 1), tb, 0, stream>>>(W1, Wt1, 500, 300);
    transpose_rc<<<dim3(16,  7, 1), tb, 0, stream>>>(W2, Wt2, 200, 500);
    transpose_rc<<<dim3( 7, 16, 1), tb, 0, stream>>>(W3, Wt3, 500, 200);
    transpose_rc<<<dim3(16, 10, 1), tb, 0, stream>>>(W4, Wt4, 300, 500);
    // Input spikes [B,IN,T] -> [B,T,IN]
    transpose_rc<<<dim3(10, 10, B), tb, 0, stream>>>(inputs, reg2, 300, 300);

    // Layer 1: 300 -> 500
    spmm_snn<<<dim3(4, 10, B), 256, 0, stream>>>(reg2, Wt1, c1, 300, 500, T);
    lif_t<<<dim3(8, B), 64, 0, stream>>>(c1, bias1, a1_1, a2_1, b_1, 500);
    // Layer 2: 500 -> 200
    spmm_snn<<<dim3(2, 10, B), 256, 0, stream>>>(c1, Wt2, c2, 500, 200, T);
    lif_t<<<dim3(4, B), 64, 0, stream>>>(c2, bias2, a1_2, a2_2, b_2, 200);
    // Layer 3: 200 -> 500 (write into c1; s1 dead)
    spmm_snn<<<dim3(4, 10, B), 256, 0, stream>>>(c2, Wt3, c1, 200, 500, T);
    lif_t<<<dim3(8, B), 64, 0, stream>>>(c1, bias3, a1_3, a2_3, b_3, 500);
    // Layer 4: 500 -> 300 into reg2 (inputT dead); LIF+filter, filt_tmp -> c1
    spmm_snn<<<dim3(3, 10, B), 256, 0, stream>>>(c1, Wt4, reg2, 500, 300, T);
    lif4_t<<<dim3(5, B), 64, 0, stream>>>(reg2, c1, bias4, a1_4, a2_4, b_4, 300);

    // Final transposes [B,T,O] -> [B,O,T]: s4 first (frees reg2), then filt.
    transpose_rc<<<dim3(10, 10, B), tb, 0, stream>>>(reg2, reg1, 300, 300);
    transpose_rc<<<dim3(10, 10, B), tb, 0, stream>>>(c1, reg2, 300, 300);
}

// Round 6
// 531.072 us; speedup vs baseline: 1.2823x; 1.1760x over previous
//
#include <hip/hip_runtime.h>

// ---- filter / neuron constants (double, matching the Python reference) ----
#define EMD 0.8824969025845955      // exp(-1/8)
#define ESD 0.6065306597126334      // exp(-1/2)
#define A1C ((float)(EMD + ESD))                    // y[t-1] coeff
#define A2C ((float)(-(EMD * ESD)))                 // y[t-2] coeff
#define BC  ((float)((8.0 / 6.0) * (EMD - ESD)))    // x[t] coeff (ETA=8/6)
#define EMF ((float)EMD)                            // reset decay

// B=64, T=300. Layers: 300 -> 500 -> 200 -> 500 -> 300.
//
// Exactness contract (absmax 0.0, rounds 1-5): reference currents are a
// SEQUENTIAL ascending-i fp32 fold of W[o,i]*s[i]; spikes are exactly 0/1.
// Skipping s==0 terms is bitwise-neutral; processing set bits in ascending
// order is the SAME add sequence. The 4-wide unroll below preserves that
// order exactly (j0<j1<j2<j3, groups sequential).

// ---------------------------------------------------------------------------
// Generic batched transpose: src [Bt][R][C] -> dst [Bt][C][R]
// ---------------------------------------------------------------------------
__global__ __launch_bounds__(256) void transpose_rc(
    const float* __restrict__ src, float* __restrict__ dst, int R, int C)
{
    __shared__ float tile[32][33];
    const int c0 = blockIdx.x * 32;
    const int r0 = blockIdx.y * 32;
    const int b  = blockIdx.z;
    const float* S = src + (size_t)b * R * C;
    float* D = dst + (size_t)b * R * C;
    const int tx = threadIdx.x;      // 0..31
    const int ty = threadIdx.y;      // 0..7
#pragma unroll
    for (int s = 0; s < 4; s++) {
        const int r = r0 + ty + 8 * s;
        const int c = c0 + tx;
        if (r < R && c < C) tile[ty + 8 * s][tx] = S[(size_t)r * C + c];
    }
    __syncthreads();
#pragma unroll
    for (int s = 0; s < 4; s++) {
        const int c = c0 + ty + 8 * s;
        const int r = r0 + tx;
        if (c < C && r < R) D[(size_t)c * R + r] = tile[tx][ty + 8 * s];
    }
}

// ---------------------------------------------------------------------------
// Sparse spike GEMM: C[b,t,o] = sum_i Wt[i,o] * S[b,t,i], skipping S==0.
// S: [B,T,K] binary, Wt: [K,O], C: [B,T,O].
// Block: 256 thr (4 waves), o-chunk 128 (2 o's/lane), t-chunk 32 (8 t/wave),
// K staged in 64-row LDS chunks (32 KB), register-prefetched one chunk ahead.
// Bit loop is 4-wide unrolled: 4 independent ds_read_b64 in flight per group
// (round-5 was 1 -> latency-bound at VALUBusy 19%).
// ---------------------------------------------------------------------------
#define KG  64
#define OCN 128
#define TCN 32

__global__ __launch_bounds__(256) void spmm_snn(
    const float* __restrict__ S, const float* __restrict__ Wt,
    float* __restrict__ C, int K, int O, int T)
{
    __shared__ float Wls[KG * OCN];   // 32 KB
    const int tid  = threadIdx.x;
    const int lane = tid & 63;
    const int wv   = tid >> 6;        // 0..3
    const int oc   = blockIdx.x * OCN;
    const int t0   = blockIdx.y * TCN;
    const int b    = blockIdx.z;

    const float* Sb = S + (size_t)b * T * K;
    float* Cb = C + (size_t)b * T * O;

    // staging decomposition: idx -> (row 0..63, col4 0..124)
    const int srow  = tid >> 5;        // base row (stride 8 over r)
    const int scol4 = (tid & 31) * 4;

    float2 acc[8];
#pragma unroll
    for (int u = 0; u < 8; u++) acc[u] = make_float2(0.f, 0.f);

    const int nkc = (K + KG - 1) / KG;
    float4 wpf[8];

#define LOADW(kc)                                                              \
    {                                                                          \
        const int kb_ = (kc) * KG;                                             \
        _Pragma("unroll")                                                      \
        for (int r = 0; r < 8; r++) {                                          \
            const int k = kb_ + srow + r * 8;                                  \
            const int o = oc + scol4;                                          \
            float4 w = make_float4(0.f, 0.f, 0.f, 0.f);                        \
            if (k < K && o + 3 < O)                                            \
                w = *reinterpret_cast<const float4*>(&Wt[(size_t)k * O + o]);  \
            wpf[r] = w;                                                        \
        }                                                                      \
    }

#define STOREW()                                                               \
    {                                                                          \
        _Pragma("unroll")                                                      \
        for (int r = 0; r < 8; r++)                                            \
            *reinterpret_cast<float4*>(&Wls[(srow + r * 8) * OCN + scol4]) = wpf[r]; \
    }

    LOADW(0)
    STOREW()
    __syncthreads();

    const float* wlane = &Wls[lane * 2];   // row j lives at offset j*OCN

    for (int kc = 0; kc < nkc; kc++) {
        const int kbase = kc * KG;
        if (kc + 1 < nkc) LOADW(kc + 1)    // overlaps the bit loops below

        // batch the spike loads (independent), then ballot per t
        float sv[8];
        const int k = kbase + lane;
#pragma unroll
        for (int u = 0; u < 8; u++) {
            const int t = t0 + u * 4 + wv;            // wave-uniform
            sv[u] = (t < T && k < K) ? Sb[(size_t)t * K + k] : 0.0f;
        }
#pragma unroll
        for (int u = 0; u < 8; u++) {
            unsigned long long mask = __ballot(sv[u] != 0.0f);
            int n = __popcll(mask);
            float ax = acc[u].x, ay = acc[u].y;
            while (n >= 4) {
                const int j0 = __builtin_ctzll(mask); mask &= mask - 1;
                const int j1 = __builtin_ctzll(mask); mask &= mask - 1;
                const int j2 = __builtin_ctzll(mask); mask &= mask - 1;
                const int j3 = __builtin_ctzll(mask); mask &= mask - 1;
                const float2 w0 = *reinterpret_cast<const float2*>(&wlane[j0 * OCN]);
                const float2 w1 = *reinterpret_cast<const float2*>(&wlane[j1 * OCN]);
                const float2 w2 = *reinterpret_cast<const float2*>(&wlane[j2 * OCN]);
                const float2 w3 = *reinterpret_cast<const float2*>(&wlane[j3 * OCN]);
                ax += w0.x; ay += w0.y;
                ax += w1.x; ay += w1.y;
                ax += w2.x; ay += w2.y;
                ax += w3.x; ay += w3.y;
                n -= 4;
            }
            while (n > 0) {
                const int j0 = __builtin_ctzll(mask); mask &= mask - 1;
                const float2 w0 = *reinterpret_cast<const float2*>(&wlane[j0 * OCN]);
                ax += w0.x; ay += w0.y;
                n--;
            }
            acc[u].x = ax; acc[u].y = ay;
        }
        if (kc + 1 < nkc) {
            __syncthreads();
            STOREW()
            __syncthreads();
        }
    }
#pragma unroll
    for (int u = 0; u < 8; u++) {
        const int t = t0 + u * 4 + wv;
        const int o = oc + lane * 2;
        if (t < T && o + 1 < O)               // O even -> pair all-or-nothing
            *reinterpret_cast<float2*>(&Cb[(size_t)t * O + o]) = acc[u];
    }
}

// ---------------------------------------------------------------------------
// LIF in time-major layout, in-place: C[b,t,o] currents -> spikes.
// One thread per (b,o); strided (stride O) column walk with 8-deep unrolled
// prefetch ring (constant indices -> stays in VGPRs). T fixed at 300.
// ---------------------------------------------------------------------------
#define LIF_STEP_S(xval, sval)                                                 \
    {                                                                          \
        const float y = A1 * y1 + A2 * y2 + Bc * (xval); y2 = y1; y1 = y;      \
        const float v = y + bi + r;                                            \
        sval = (v >= 1.0f) ? 1.0f : 0.0f;                                      \
        r = r * EMF - sval;                                                    \
    }

__global__ __launch_bounds__(64) void lif_t(
    float* __restrict__ C, const float* __restrict__ bias,
    const float* __restrict__ a1p, const float* __restrict__ a2p,
    const float* __restrict__ bp, int O)
{
    const int o = blockIdx.x * 64 + threadIdx.x;
    const int b = blockIdx.y;
    if (o >= O) return;
    const float A1 = a1p[0], A2 = a2p[0], Bc = bp[0];
    const float bi = bias[o];
    float* col = C + (size_t)b * 300 * O + o;

    float pf[8];
#pragma unroll
    for (int u = 0; u < 8; u++) pf[u] = col[(size_t)u * O];

    float y1 = 0.f, y2 = 0.f, r = 0.f;
    for (int blk = 0; blk < 37; blk++) {       // t = 0..295
#pragma unroll
        for (int u = 0; u < 8; u++) {
            const int t = blk * 8 + u;
            const float x = pf[u];
            if (t + 8 < 300) pf[u] = col[(size_t)(t + 8) * O];
            float s;
            LIF_STEP_S(x, s)
            col[(size_t)t * O] = s;
        }
    }
#pragma unroll
    for (int u = 0; u < 4; u++) {              // t = 296..299
        const float x = pf[u];
        float s;
        LIF_STEP_S(x, s)
        col[(size_t)(296 + u) * O] = s;
    }
}

// ---------------------------------------------------------------------------
// Layer-4 LIF + fixed output dual-exp IIR. C: currents->spikes (in place),
// F: filtered output. Both [B,T,O], O=300.
// ---------------------------------------------------------------------------
__global__ __launch_bounds__(64) void lif4_t(
    float* __restrict__ C, float* __restrict__ F,
    const float* __restrict__ bias,
    const float* __restrict__ a1p, const float* __restrict__ a2p,
    const float* __restrict__ bp, int O)
{
    const int o = blockIdx.x * 64 + threadIdx.x;
    const int b = blockIdx.y;
    if (o >= O) return;
    const float A1 = a1p[0], A2 = a2p[0], Bc = bp[0];
    const float bi = bias[o];
    float* col  = C + (size_t)b * 300 * O + o;
    float* fcol = F + (size_t)b * 300 * O + o;

    float pf[8];
#pragma unroll
    for (int u = 0; u < 8; u++) pf[u] = col[(size_t)u * O];

    float y1 = 0.f, y2 = 0.f, r = 0.f;
    float z1 = 0.f, z2 = 0.f;
    for (int blk = 0; blk < 37; blk++) {
#pragma unroll
        for (int u = 0; u < 8; u++) {
            const int t = blk * 8 + u;
            const float x = pf[u];
            if (t + 8 < 300) pf[u] = col[(size_t)(t + 8) * O];
            float s;
            LIF_STEP_S(x, s)
            const float z = A1C * z1 + A2C * z2 + BC * s; z2 = z1; z1 = z;
            col[(size_t)t * O]  = s;
            fcol[(size_t)t * O] = z;
        }
    }
#pragma unroll
    for (int u = 0; u < 4; u++) {
        const int t = 296 + u;
        const float x = pf[u];
        float s;
        LIF_STEP_S(x, s)
        const float z = A1C * z1 + A2C * z2 + BC * s; z2 = z1; z1 = z;
        col[(size_t)t * O]  = s;
        fcol[(size_t)t * O] = z;
    }
}

// ---------------------------------------------------------------------------
extern "C" void kernel_launch(void* const* d_in, const int* in_sizes, int n_in,
                              void* d_out, int out_size, void* d_ws, size_t ws_size,
                              hipStream_t stream)
{
    const float* inputs = (const float*)d_in[0];           // [64,300,300] binary
    const float* a1_1 = (const float*)d_in[1];
    const float* a2_1 = (const float*)d_in[2];
    const float* b_1  = (const float*)d_in[3];
    const float* W1   = (const float*)d_in[4];             // [500,300]
    const float* bias1= (const float*)d_in[5];
    const float* a1_2 = (const float*)d_in[6];
    const float* a2_2 = (const float*)d_in[7];
    const float* b_2  = (const float*)d_in[8];
    const float* W2   = (const float*)d_in[9];             // [200,500]
    const float* bias2= (const float*)d_in[10];
    const float* a1_3 = (const float*)d_in[11];
    const float* a2_3 = (const float*)d_in[12];
    const float* b_3  = (const float*)d_in[13];
    const float* W3   = (const float*)d_in[14];            // [500,200]
    const float* bias3= (const float*)d_in[15];
    const float* a1_4 = (const float*)d_in[16];
    const float* a2_4 = (const float*)d_in[17];
    const float* b_4  = (const float*)d_in[18];
    const float* W4   = (const float*)d_in[19];            // [300,500]
    const float* bias4= (const float*)d_in[20];

    const int B = 64, T = 300;

    // Workspace (proven size 53.76 MB): c1 = 9.6M floats, c2 = 3.84M floats.
    float* ws = (float*)d_ws;
    float* c1 = ws;                 // [B,T,500]; later filt_tmp [B,T,300]
    float* c2 = ws + 9600000;       // [B,T,200]

    // d_out regions double as scratch until the final transposes:
    // region1 [0..5.76M): Wt1..4 (500K floats), later final s4 [B,O,T]
    // region2 [5.76M..11.52M): inputT/c4/s4_tmp [B,T,300], later final filt
    float* out = (float*)d_out;
    float* reg1 = out;
    float* reg2 = out + 5760000;
    float* Wt1 = reg1;              // [300,500] = 150000
    float* Wt2 = reg1 + 150000;     // [500,200] = 100000
    float* Wt3 = reg1 + 250000;     // [200,500] = 100000
    float* Wt4 = reg1 + 350000;     // [500,300] = 150000

    const dim3 tb(32, 8);

    // Weight transposes W[O,K] -> Wt[K,O]
    transpose_rc<<<dim3(10, 16, 1), tb, 0, stream>>>(W1, Wt1, 500, 300);
    transpose_rc<<<dim3(16,  7, 1), tb, 0, stream>>>(W2, Wt2, 200, 500);
    transpose_rc<<<dim3( 7, 16, 1), tb, 0, stream>>>(W3, Wt3, 500, 200);
    transpose_rc<<<dim3(16, 10, 1), tb, 0, stream>>>(W4, Wt4, 300, 500);
    // Input spikes [B,IN,T] -> [B,T,IN]
    transpose_rc<<<dim3(10, 10, B), tb, 0, stream>>>(inputs, reg2, 300, 300);

    // Layer 1: 300 -> 500
    spmm_snn<<<dim3(4, 10, B), 256, 0, stream>>>(reg2, Wt1, c1, 300, 500, T);
    lif_t<<<dim3(8, B), 64, 0, stream>>>(c1, bias1, a1_1, a2_1, b_1, 500);
    // Layer 2: 500 -> 200
    spmm_snn<<<dim3(2, 10, B), 256, 0, stream>>>(c1, Wt2, c2, 500, 200, T);
    lif_t<<<dim3(4, B), 64, 0, stream>>>(c2, bias2, a1_2, a2_2, b_2, 200);
    // Layer 3: 200 -> 500 (write into c1; s1 dead)
    spmm_snn<<<dim3(4, 10, B), 256, 0, stream>>>(c2, Wt3, c1, 200, 500, T);
    lif_t<<<dim3(8, B), 64, 0, stream>>>(c1, bias3, a1_3, a2_3, b_3, 500);
    // Layer 4: 500 -> 300 into reg2 (inputT dead); LIF+filter, filt_tmp -> c1
    spmm_snn<<<dim3(3, 10, B), 256, 0, stream>>>(c1, Wt4, reg2, 500, 300, T);
    lif4_t<<<dim3(5, B), 64, 0, stream>>>(reg2, c1, bias4, a1_4, a2_4, b_4, 300);

    // Final transposes [B,T,O] -> [B,O,T]: s4 first (frees reg2), then filt.
    transpose_rc<<<dim3(10, 10, B), tb, 0, stream>>>(reg2, reg1, 300, 300);
    transpose_rc<<<dim3(10, 10, B), tb, 0, stream>>>(c1, reg2, 300, 300);
}